// Round 12
// baseline (275.068 us; speedup 1.0000x reference)
//
#include <hip/hip_runtime.h>
#include <math.h>
#include <float.h>

#define D 256
#define NBLK 512
#define TPB 512                 // 8 waves per block
#define WPB (TPB / 64)

// ---------------------------------------------------------------------------
// wave-wide reductions
// ---------------------------------------------------------------------------
__device__ __forceinline__ float wave_reduce_sum(float s) {
    s += __shfl_xor(s, 32);
    s += __shfl_xor(s, 16);
    s += __shfl_xor(s, 8);
    s += __shfl_xor(s, 4);
    s += __shfl_xor(s, 2);
    s += __shfl_xor(s, 1);
    return s;
}
__device__ __forceinline__ float wave_reduce_max(float s) {
    s = fmaxf(s, __shfl_xor(s, 32));
    s = fmaxf(s, __shfl_xor(s, 16));
    s = fmaxf(s, __shfl_xor(s, 8));
    s = fmaxf(s, __shfl_xor(s, 4));
    s = fmaxf(s, __shfl_xor(s, 2));
    s = fmaxf(s, __shfl_xor(s, 1));
    return s;
}

// ---------------------------------------------------------------------------
// K0: u = B @ q ; v = A^T @ u   (1 block, 1024 threads)
// ---------------------------------------------------------------------------
__global__ __launch_bounds__(1024) void mr_init(const float* __restrict__ q,
                                                const float* __restrict__ Bm,
                                                const float* __restrict__ Am,
                                                float* __restrict__ u,
                                                float* __restrict__ v) {
    __shared__ __align__(16) float sq[D];
    __shared__ float su[D];
    __shared__ float part[4][D];
    const int tid = threadIdx.x;

    if (tid < D) sq[tid] = q[tid];
    __syncthreads();
    {
        const int j = tid >> 2, qd = tid & 3;
        const float4* Br = (const float4*)(Bm + (size_t)j * D + qd * 64);
        const float4* qr = (const float4*)(sq + qd * 64);
        float acc = 0.f;
#pragma unroll
        for (int i = 0; i < 16; ++i) {
            float4 b4 = Br[i];
            float4 q4 = qr[i];
            acc += b4.x * q4.x + b4.y * q4.y + b4.z * q4.z + b4.w * q4.w;
        }
        part[qd][j] = acc;
    }
    __syncthreads();
    if (tid < D) {
        float uu = part[0][tid] + part[1][tid] + part[2][tid] + part[3][tid];
        u[tid] = uu;
        su[tid] = uu;
    }
    __syncthreads();
    {
        const int k = tid & (D - 1), h = tid >> 8;
        const int j0 = h * 64;
        float acc = 0.f;
#pragma unroll 8
        for (int jj = 0; jj < 64; ++jj)
            acc += Am[(size_t)(j0 + jj) * D + k] * su[j0 + jj];
        part[h][k] = acc;
    }
    __syncthreads();
    if (tid < D)
        v[tid] = part[0][tid] + part[1][tid] + part[2][tid] + part[3][tid];
}

// ---------------------------------------------------------------------------
// Main pass, 16-lane-group layout: each wave processes 4 slots at a time
// (group g = lane>>4 owns slot base+g; lane holds 16 columns of that slot).
// One 4-step shuffle reduce serves all 4 slots; online-softmax state is
// per-lane (m, Z, w[16]).
// ---------------------------------------------------------------------------
__global__ __launch_bounds__(TPB) void mr_pass(
        const float* __restrict__ mem, const float* __restrict__ v,
        float* __restrict__ wsM, float* __restrict__ wsZ,
        float* __restrict__ wsW, int nslots, int nwavesTotal) {
    const int tid  = threadIdx.x;
    const int lane = tid & 63;
    const int wid  = tid >> 6;
    const int l16  = lane & 15;
    const int g    = lane >> 4;
    const int gwave = blockIdx.x * WPB + wid;

    const int slab = (nslots + nwavesTotal - 1) / nwavesTotal;
    const int s0 = gwave * slab;
    const int s1 = min(s0 + slab, nslots);

    const float4 v0 = ((const float4*)v)[l16];
    const float4 v1 = ((const float4*)v)[l16 + 16];
    const float4 v2 = ((const float4*)v)[l16 + 32];
    const float4 v3 = ((const float4*)v)[l16 + 48];

    float m = -FLT_MAX, Z = 0.f;
    float4 w0 = {0,0,0,0}, w1 = {0,0,0,0}, w2 = {0,0,0,0}, w3 = {0,0,0,0};

    for (int base = s0; base < s1; base += 8) {
        const int slotA = base + g;
        const int slotB = base + 4 + g;
        const bool vA = slotA < s1;
        const bool vB = slotB < s1;
        const int cA = vA ? slotA : s0;
        const int cB = vB ? slotB : s0;
        const float4* rA = (const float4*)(mem + (size_t)cA * D);
        const float4* rB = (const float4*)(mem + (size_t)cB * D);
        float4 a0 = rA[l16], a1 = rA[l16 + 16], a2 = rA[l16 + 32], a3 = rA[l16 + 48];
        float4 b0 = rB[l16], b1 = rB[l16 + 16], b2 = rB[l16 + 32], b3 = rB[l16 + 48];

        float pA = a0.x*v0.x + a0.y*v0.y + a0.z*v0.z + a0.w*v0.w
                 + a1.x*v1.x + a1.y*v1.y + a1.z*v1.z + a1.w*v1.w
                 + a2.x*v2.x + a2.y*v2.y + a2.z*v2.z + a2.w*v2.w
                 + a3.x*v3.x + a3.y*v3.y + a3.z*v3.z + a3.w*v3.w;
        float pB = b0.x*v0.x + b0.y*v0.y + b0.z*v0.z + b0.w*v0.w
                 + b1.x*v1.x + b1.y*v1.y + b1.z*v1.z + b1.w*v1.w
                 + b2.x*v2.x + b2.y*v2.y + b2.z*v2.z + b2.w*v2.w
                 + b3.x*v3.x + b3.y*v3.y + b3.z*v3.z + b3.w*v3.w;
        pA += __shfl_xor(pA, 1);  pB += __shfl_xor(pB, 1);
        pA += __shfl_xor(pA, 2);  pB += __shfl_xor(pB, 2);
        pA += __shfl_xor(pA, 4);  pB += __shfl_xor(pB, 4);
        pA += __shfl_xor(pA, 8);  pB += __shfl_xor(pB, 8);

        // ---- update A ----
        {
            float sv = vA ? pA : -FLT_MAX;
            float mn = fmaxf(m, sv);
            float e  = vA ? __expf(sv - mn) : 0.f;
            if (__any(mn > m)) {
                float sc = __expf(m - mn);
                Z = Z * sc + e;
                w0.x = w0.x*sc + e*a0.x; w0.y = w0.y*sc + e*a0.y; w0.z = w0.z*sc + e*a0.z; w0.w = w0.w*sc + e*a0.w;
                w1.x = w1.x*sc + e*a1.x; w1.y = w1.y*sc + e*a1.y; w1.z = w1.z*sc + e*a1.z; w1.w = w1.w*sc + e*a1.w;
                w2.x = w2.x*sc + e*a2.x; w2.y = w2.y*sc + e*a2.y; w2.z = w2.z*sc + e*a2.z; w2.w = w2.w*sc + e*a2.w;
                w3.x = w3.x*sc + e*a3.x; w3.y = w3.y*sc + e*a3.y; w3.z = w3.z*sc + e*a3.z; w3.w = w3.w*sc + e*a3.w;
                m = mn;
            } else {
                Z += e;
                w0.x += e*a0.x; w0.y += e*a0.y; w0.z += e*a0.z; w0.w += e*a0.w;
                w1.x += e*a1.x; w1.y += e*a1.y; w1.z += e*a1.z; w1.w += e*a1.w;
                w2.x += e*a2.x; w2.y += e*a2.y; w2.z += e*a2.z; w2.w += e*a2.w;
                w3.x += e*a3.x; w3.y += e*a3.y; w3.z += e*a3.z; w3.w += e*a3.w;
            }
        }
        // ---- update B ----
        {
            float sv = vB ? pB : -FLT_MAX;
            float mn = fmaxf(m, sv);
            float e  = vB ? __expf(sv - mn) : 0.f;
            if (__any(mn > m)) {
                float sc = __expf(m - mn);
                Z = Z * sc + e;
                w0.x = w0.x*sc + e*b0.x; w0.y = w0.y*sc + e*b0.y; w0.z = w0.z*sc + e*b0.z; w0.w = w0.w*sc + e*b0.w;
                w1.x = w1.x*sc + e*b1.x; w1.y = w1.y*sc + e*b1.y; w1.z = w1.z*sc + e*b1.z; w1.w = w1.w*sc + e*b1.w;
                w2.x = w2.x*sc + e*b2.x; w2.y = w2.y*sc + e*b2.y; w2.z = w2.z*sc + e*b2.z; w2.w = w2.w*sc + e*b2.w;
                w3.x = w3.x*sc + e*b3.x; w3.y = w3.y*sc + e*b3.y; w3.z = w3.z*sc + e*b3.z; w3.w = w3.w*sc + e*b3.w;
                m = mn;
            } else {
                Z += e;
                w0.x += e*b0.x; w0.y += e*b0.y; w0.z += e*b0.z; w0.w += e*b0.w;
                w1.x += e*b1.x; w1.y += e*b1.y; w1.z += e*b1.z; w1.w += e*b1.w;
                w2.x += e*b2.x; w2.y += e*b2.y; w2.z += e*b2.z; w2.w += e*b2.w;
                w3.x += e*b3.x; w3.y += e*b3.y; w3.z += e*b3.z; w3.w += e*b3.w;
            }
        }
    }

    // ---- block combine: 8 waves x 4 groups = 32 partials ----
    __shared__ __align__(16) float lw[WPB * 4][D];
    __shared__ float lm[WPB * 4];
    __shared__ float lz[WPB * 4];
    __shared__ float lf[WPB * 4];
    const int grp = wid * 4 + g;
    *(float4*)&lw[grp][(l16 +  0) * 4] = w0;
    *(float4*)&lw[grp][(l16 + 16) * 4] = w1;
    *(float4*)&lw[grp][(l16 + 32) * 4] = w2;
    *(float4*)&lw[grp][(l16 + 48) * 4] = w3;
    if (l16 == 0) { lm[grp] = m; lz[grp] = Z; }
    __syncthreads();

    if (tid < 32) {
        float mm = lm[tid];
        float M = mm;
        M = fmaxf(M, __shfl_xor(M, 1));
        M = fmaxf(M, __shfl_xor(M, 2));
        M = fmaxf(M, __shfl_xor(M, 4));
        M = fmaxf(M, __shfl_xor(M, 8));
        M = fmaxf(M, __shfl_xor(M, 16));
        float fv = __expf(mm - M);
        lf[tid] = fv;
        float zf = lz[tid] * fv;
        zf += __shfl_xor(zf, 1);
        zf += __shfl_xor(zf, 2);
        zf += __shfl_xor(zf, 4);
        zf += __shfl_xor(zf, 8);
        zf += __shfl_xor(zf, 16);
        if (tid == 0) { wsM[blockIdx.x] = M; wsZ[blockIdx.x] = zf; }
    }
    __syncthreads();

    if (tid < D) {
        float wacc = 0.f;
#pragma unroll
        for (int p = 0; p < WPB * 4; ++p) wacc += lw[p][tid] * lf[p];
        wsW[(size_t)blockIdx.x * D + tid] = wacc;
    }
}

// ---------------------------------------------------------------------------
// Combine partials (parallel), o = C (w/Z), u += o, v = A^T u
// ---------------------------------------------------------------------------
__global__ __launch_bounds__(1024) void mr_combine(
        const float* __restrict__ wsM, const float* __restrict__ wsZ,
        const float* __restrict__ wsW, const float* __restrict__ Cm,
        const float* __restrict__ Am, float* __restrict__ u,
        float* __restrict__ v, float* __restrict__ out, int nb, int last) {
    __shared__ float f[NBLK];
    __shared__ float red[16];
    __shared__ float sMZ[2];
    __shared__ float part[4][D];
    __shared__ __align__(16) float sw[D];
    __shared__ float su[D];
    const int tid = threadIdx.x;
    const int lane = tid & 63, wv = tid >> 6;

    float lm = -FLT_MAX;
    for (int b = tid; b < nb; b += 1024) lm = fmaxf(lm, wsM[b]);
    lm = wave_reduce_max(lm);
    if (lane == 0) red[wv] = lm;
    __syncthreads();
    if (tid == 0) {
        float M = red[0];
#pragma unroll
        for (int i = 1; i < 16; ++i) M = fmaxf(M, red[i]);
        sMZ[0] = M;
    }
    __syncthreads();
    const float M = sMZ[0];

    float zp = 0.f;
    for (int b = tid; b < nb; b += 1024) {
        float fb = __expf(wsM[b] - M);
        f[b] = fb;
        zp += wsZ[b] * fb;
    }
    zp = wave_reduce_sum(zp);
    if (lane == 0) red[wv] = zp;
    __syncthreads();
    if (tid == 0) {
        float Z = 0.f;
#pragma unroll
        for (int i = 0; i < 16; ++i) Z += red[i];
        sMZ[1] = Z;
    }
    __syncthreads();
    const float Z = sMZ[1];

    {
        const int c = tid & (D - 1);
        const int chunk = tid >> 8;
        const int bpc = nb >> 2;
        const int b0 = chunk * bpc, b1 = b0 + bpc;
        float acc = 0.f;
#pragma unroll 8
        for (int b = b0; b < b1; ++b)
            acc += wsW[(size_t)b * D + c] * f[b];
        part[chunk][c] = acc;
    }
    __syncthreads();
    if (tid < D)
        sw[tid] = (part[0][tid] + part[1][tid] + part[2][tid] + part[3][tid]) / Z;
    __syncthreads();

    {
        const int j = tid >> 2, qd = tid & 3;
        const float4* Cr = (const float4*)(Cm + (size_t)j * D + qd * 64);
        const float4* wr = (const float4*)(sw + qd * 64);
        float acc = 0.f;
#pragma unroll
        for (int i = 0; i < 16; ++i) {
            float4 c4 = Cr[i];
            float4 w4 = wr[i];
            acc += c4.x * w4.x + c4.y * w4.y + c4.z * w4.z + c4.w * w4.w;
        }
        part[qd][j] = acc;
    }
    __syncthreads();
    if (tid < D) {
        float o = part[0][tid] + part[1][tid] + part[2][tid] + part[3][tid];
        float un = u[tid] + o;
        u[tid] = un;
        su[tid] = un;
        if (last) out[tid] = un;
    }
    __syncthreads();

    if (!last) {
        const int k = tid & (D - 1), h = tid >> 8;
        const int j0 = h * 64;
        float acc = 0.f;
#pragma unroll 8
        for (int jj = 0; jj < 64; ++jj)
            acc += Am[(size_t)(j0 + jj) * D + k] * su[j0 + jj];
        part[h][k] = acc;
        __syncthreads();
        if (tid < D)
            v[tid] = part[0][tid] + part[1][tid] + part[2][tid] + part[3][tid];
    }
}

// ---------------------------------------------------------------------------
extern "C" void kernel_launch(void* const* d_in, const int* in_sizes, int n_in,
                              void* d_out, int out_size, void* d_ws, size_t ws_size,
                              hipStream_t stream) {
    const float* mem = (const float*)d_in[0];
    const float* q   = (const float*)d_in[1];
    const float* A   = (const float*)d_in[2];
    const float* B   = (const float*)d_in[3];
    const float* C   = (const float*)d_in[4];
    float* out = (float*)d_out;
    float* ws  = (float*)d_ws;

    const int nslots = in_sizes[0] / D;

    long wsf = (long)(ws_size / 4);
    int nb = NBLK;
    long need = 2L * D + (long)nb * (2 + D);
    if (need > wsf) {
        nb = (int)((wsf - 2L * D) / (2 + D));
        nb &= ~3;
        if (nb < 4) nb = 4;
    }

    float* u   = ws;
    float* v   = ws + D;
    float* wsM = ws + 2 * D;
    float* wsZ = wsM + nb;
    float* wsW = wsZ + nb;

    mr_init<<<1, 1024, 0, stream>>>(q, B, A, u, v);
    for (int hop = 0; hop < 3; ++hop) {
        mr_pass<<<nb, TPB, 0, stream>>>(mem, v, wsM, wsZ, wsW,
                                        nslots, nb * WPB);
        mr_combine<<<1, 1024, 0, stream>>>(wsM, wsZ, wsW, C, A, u, v, out,
                                           nb, hop == 2 ? 1 : 0);
    }
}